// Round 1
// baseline (1247.157 us; speedup 1.0000x reference)
//
#include <hip/hip_runtime.h>
#include <hip/hip_bf16.h>
#include <cstdio>

#define N_NODES 100000
#define E_EDGES 3200000
#define N_GRAPH 512
#define HDIM 64
#define BN_EPS 1e-5f

// ---------------- CSR build ----------------

__global__ void count_k(const int* __restrict__ dst, int* __restrict__ deg) {
    int e = blockIdx.x * 256 + threadIdx.x;
    if (e < E_EDGES) atomicAdd(&deg[dst[e]], 1);
}

__global__ void dinv_k(const int* __restrict__ deg, float* __restrict__ dinv) {
    int v = blockIdx.x * 256 + threadIdx.x;
    if (v < N_NODES) dinv[v] = rsqrtf((float)(deg[v] + 1));
}

__global__ void scan1_k(const int* __restrict__ deg, int* __restrict__ ptr,
                        int* __restrict__ bsum) {
    __shared__ int sh[256];
    int t = threadIdx.x;
    int i = blockIdx.x * 256 + t;
    int v = (i < N_NODES) ? deg[i] : 0;
    sh[t] = v;
    __syncthreads();
    for (int off = 1; off < 256; off <<= 1) {
        int add = (t >= off) ? sh[t - off] : 0;
        __syncthreads();
        sh[t] += add;
        __syncthreads();
    }
    if (i < N_NODES) ptr[i] = sh[t] - v;      // exclusive within block
    if (t == 255) bsum[blockIdx.x] = sh[255]; // block total
}

__global__ void scan2_k(int* __restrict__ bsum, int nb) {
    __shared__ int sh[512];
    int t = threadIdx.x;
    int v = (t < nb) ? bsum[t] : 0;
    sh[t] = v;
    __syncthreads();
    for (int off = 1; off < 512; off <<= 1) {
        int add = (t >= off) ? sh[t - off] : 0;
        __syncthreads();
        sh[t] += add;
        __syncthreads();
    }
    if (t < nb) bsum[t] = sh[t] - v; // exclusive block offsets
}

__global__ void scan3_k(int* __restrict__ ptr, const int* __restrict__ bsum) {
    int i = blockIdx.x * 256 + threadIdx.x;
    if (i < N_NODES) ptr[i] += bsum[i >> 8];
    if (i == 0) ptr[N_NODES] = E_EDGES;
}

__global__ void fill_k(const int* __restrict__ src, const int* __restrict__ dst,
                       const int* __restrict__ ptr, int* __restrict__ fillc,
                       int* __restrict__ csr, float* __restrict__ csrw,
                       const float* __restrict__ dinv) {
    int e = blockIdx.x * 256 + threadIdx.x;
    if (e >= E_EDGES) return;
    int v = dst[e];
    int u = src[e];
    int k = atomicAdd(&fillc[v], 1);
    int pos = ptr[v] + k;
    csr[pos] = u;
    csrw[pos] = dinv[u];
}

// ---------------- Layer 1 (rank-1: scalar aggregation) ----------------

__global__ void l1_gather_k(const float* __restrict__ x, const int* __restrict__ ptr,
                            const int* __restrict__ csr, const float* __restrict__ csrw,
                            const float* __restrict__ dinv, float* __restrict__ sbuf) {
    int v = blockIdx.x * 256 + threadIdx.x;
    if (v >= N_NODES) return;
    float dv = dinv[v];
    float s = dv * dv * x[v];
    int e1 = ptr[v + 1];
    for (int e = ptr[v]; e < e1; e++) {
        s += dv * csrw[e] * x[csr[e]];
    }
    sbuf[v] = s;
}

__global__ void l1_expand_k(const float* __restrict__ sbuf, const float* __restrict__ w1,
                            const float* __restrict__ b1, const float* __restrict__ bg,
                            const float* __restrict__ bb, const float* __restrict__ brm,
                            const float* __restrict__ brv, float* __restrict__ xout) {
    int tid = blockIdx.x * 256 + threadIdx.x;
    if (tid >= N_NODES * HDIM) return;
    int v = tid >> 6;
    int f = tid & 63;
    float sc = bg[f] * rsqrtf(brv[f] + BN_EPS);
    float pre = sbuf[v] * w1[f] + b1[f];
    float val = (pre - brm[f]) * sc + bb[f];
    xout[tid] = fmaxf(val, 0.f);
}

// ---------------- Layers 2/3: aggregate(x) then @W + b + BN + ReLU ----------------
// Wave per node, lane = feature. x rows are coalesced 256B reads.
// GEMM folded in: since aggregation is linear, (sum coef*x[u]) @ W == sum coef*(x@W)[u].

__global__ __launch_bounds__(256) void agg_gemm_k(
    const float* __restrict__ xin, float* __restrict__ xout,
    const int* __restrict__ ptr, const int* __restrict__ csr,
    const float* __restrict__ csrw, const float* __restrict__ dinv,
    const float* __restrict__ W, const float* __restrict__ bias,
    const float* __restrict__ bg, const float* __restrict__ bb,
    const float* __restrict__ brm, const float* __restrict__ brv) {
    __shared__ float wsh[HDIM * HDIM]; // 16 KB
    __shared__ float sM[HDIM], sC[HDIM];
    int tid = threadIdx.x;
    for (int i = tid; i < HDIM * HDIM; i += 256) wsh[i] = W[i];
    if (tid < HDIM) {
        float sc = bg[tid] * rsqrtf(brv[tid] + BN_EPS);
        sM[tid] = sc;
        sC[tid] = (bias[tid] - brm[tid]) * sc + bb[tid];
    }
    __syncthreads();

    int v = (blockIdx.x << 2) + (tid >> 6); // wave id = node
    int f = tid & 63;
    if (v >= N_NODES) return;

    float dv = dinv[v];
    float acc = dv * dv * xin[(size_t)v * HDIM + f];
    int e1 = ptr[v + 1];
    for (int e = ptr[v]; e < e1; e++) {
        int u = csr[e];           // broadcast (all lanes same addr)
        float c = dv * csrw[e];   // broadcast, streamed
        acc += c * xin[(size_t)u * HDIM + f]; // coalesced 256B row
    }

    // out[f] = sum_k acc[k] * W[k][f]  via readlane broadcast
    float o = 0.f;
#pragma unroll
    for (int k = 0; k < HDIM; k++) {
        float a = __shfl(acc, k);
        o += a * wsh[(k << 6) + f]; // 2-way bank alias = free
    }
    float val = fmaxf(o * sM[f] + sC[f], 0.f);
    xout[(size_t)v * HDIM + f] = val;
}

// ---------------- Pool (mean/max per graph) + MLP head ----------------

__device__ inline int lower_bound_i(const int* __restrict__ a, int n, int val) {
    int lo = 0, hi = n;
    while (lo < hi) {
        int mid = (lo + hi) >> 1;
        if (a[mid] < val) lo = mid + 1; else hi = mid;
    }
    return lo;
}

__global__ void pool_mlp_k(const float* __restrict__ x, const int* __restrict__ batch,
                           const float* __restrict__ wl1, const float* __restrict__ bl1,
                           const float* __restrict__ wl2, const float* __restrict__ bl2,
                           const float* __restrict__ bg, const float* __restrict__ bb,
                           const float* __restrict__ brm, const float* __restrict__ brv,
                           float* __restrict__ out) {
    int g = blockIdx.x;
    int f = threadIdx.x; // 64 threads = 1 wave
    int start = lower_bound_i(batch, N_NODES, g);
    int end = lower_bound_i(batch, N_NODES, g + 1);
    float sum = 0.f;
    float mx = -3.402823466e38f;
    for (int v = start; v < end; v++) {
        float val = x[(size_t)v * HDIM + f];
        sum += val;
        mx = fmaxf(mx, val);
    }
    float cnt = (float)(end - start);
    float mean = sum / fmaxf(cnt, 1.f);

    __shared__ float zs[2 * HDIM];
    zs[f] = mean;
    zs[HDIM + f] = mx;
    __syncthreads();

    float o = bl1[f];
    for (int k = 0; k < 2 * HDIM; k++) {
        o += zs[k] * wl1[k * HDIM + f];
    }
    float sc = bg[f] * rsqrtf(brv[f] + BN_EPS);
    o = (o - brm[f]) * sc + bb[f];
    o = fmaxf(o, 0.f);

    float p0 = o * wl2[f * 2 + 0];
    float p1 = o * wl2[f * 2 + 1];
    for (int off = 32; off > 0; off >>= 1) {
        p0 += __shfl_down(p0, off);
        p1 += __shfl_down(p1, off);
    }
    if (f == 0) {
        out[g * 2 + 0] = p0 + bl2[0];
        out[g * 2 + 1] = p1 + bl2[1];
    }
}

// ---------------- launch ----------------

extern "C" void kernel_launch(void* const* d_in, const int* in_sizes, int n_in,
                              void* d_out, int out_size, void* d_ws, size_t ws_size,
                              hipStream_t stream) {
    const float* x    = (const float*)d_in[0];
    const int* src    = (const int*)d_in[1];
    const int* dst    = (const int*)d_in[2];
    const int* batch  = (const int*)d_in[3];
    const float* w1   = (const float*)d_in[4];
    const float* b1   = (const float*)d_in[5];
    const float* w2   = (const float*)d_in[6];
    const float* b2   = (const float*)d_in[7];
    const float* w3   = (const float*)d_in[8];
    const float* b3   = (const float*)d_in[9];
    const float* wl1  = (const float*)d_in[10];
    const float* bl1  = (const float*)d_in[11];
    const float* wl2  = (const float*)d_in[12];
    const float* bl2  = (const float*)d_in[13];
    const float* bn1g = (const float*)d_in[14];
    const float* bn1b = (const float*)d_in[15];
    const float* bn1rm = (const float*)d_in[16];
    const float* bn1rv = (const float*)d_in[17];
    const float* bn2g = (const float*)d_in[18];
    const float* bn2b = (const float*)d_in[19];
    const float* bn2rm = (const float*)d_in[20];
    const float* bn2rv = (const float*)d_in[21];
    const float* bn3g = (const float*)d_in[22];
    const float* bn3b = (const float*)d_in[23];
    const float* bn3rm = (const float*)d_in[24];
    const float* bn3rv = (const float*)d_in[25];
    const float* bnlg = (const float*)d_in[26];
    const float* bnlb = (const float*)d_in[27];
    const float* bnlrm = (const float*)d_in[28];
    const float* bnlrv = (const float*)d_in[29];
    float* out = (float*)d_out;

    // workspace carve-up (256B aligned)
    char* ws = (char*)d_ws;
    size_t off = 0;
    auto alloc = [&](size_t bytes) -> char* {
        off = (off + 255) & ~(size_t)255;
        char* p = ws + off;
        off += bytes;
        return p;
    };
    int*   deg_i = (int*)alloc((size_t)N_NODES * 4);
    float* dinv  = (float*)alloc((size_t)N_NODES * 4);
    int*   ptr   = (int*)alloc(((size_t)N_NODES + 1) * 4);
    int*   fillc = (int*)alloc((size_t)N_NODES * 4);
    int*   bsum  = (int*)alloc(1024 * 4);
    int*   csr   = (int*)alloc((size_t)E_EDGES * 4);
    float* csrw  = (float*)alloc((size_t)E_EDGES * 4);
    float* sbuf  = (float*)alloc((size_t)N_NODES * 4);
    float* xa    = (float*)alloc((size_t)N_NODES * HDIM * 4);
    float* xb    = (float*)alloc((size_t)N_NODES * HDIM * 4);
    if (off > ws_size) {
        fprintf(stderr, "kernel_launch: ws too small (%zu > %zu)\n", off, ws_size);
    }

    const int NB_N   = (N_NODES + 255) / 256;      // 391
    const int NB_E   = (E_EDGES + 255) / 256;      // 12500
    const int NB_NH  = (N_NODES * HDIM + 255) / 256; // 25000
    const int NB_WV  = (N_NODES + 3) / 4;          // 25000 (wave/node)

    hipMemsetAsync(deg_i, 0, (size_t)N_NODES * 4, stream);
    hipMemsetAsync(fillc, 0, (size_t)N_NODES * 4, stream);

    count_k<<<NB_E, 256, 0, stream>>>(dst, deg_i);
    dinv_k<<<NB_N, 256, 0, stream>>>(deg_i, dinv);
    scan1_k<<<NB_N, 256, 0, stream>>>(deg_i, ptr, bsum);
    scan2_k<<<1, 512, 0, stream>>>(bsum, NB_N);
    scan3_k<<<NB_N, 256, 0, stream>>>(ptr, bsum);
    fill_k<<<NB_E, 256, 0, stream>>>(src, dst, ptr, fillc, csr, csrw, dinv);

    l1_gather_k<<<NB_N, 256, 0, stream>>>(x, ptr, csr, csrw, dinv, sbuf);
    l1_expand_k<<<NB_NH, 256, 0, stream>>>(sbuf, w1, b1, bn1g, bn1b, bn1rm, bn1rv, xa);

    agg_gemm_k<<<NB_WV, 256, 0, stream>>>(xa, xb, ptr, csr, csrw, dinv,
                                          w2, b2, bn2g, bn2b, bn2rm, bn2rv);
    agg_gemm_k<<<NB_WV, 256, 0, stream>>>(xb, xa, ptr, csr, csrw, dinv,
                                          w3, b3, bn3g, bn3b, bn3rm, bn3rv);

    pool_mlp_k<<<N_GRAPH, 64, 0, stream>>>(xa, batch, wl1, bl1, wl2, bl2,
                                           bnlg, bnlb, bnlrm, bnlrv, out);
}

// Round 2
// 916.580 us; speedup vs baseline: 1.3607x; 1.3607x over previous
//
#include <hip/hip_runtime.h>
#include <hip/hip_bf16.h>
#include <cstdio>

#define N_NODES 100000
#define E_EDGES 3200000
#define N_GRAPH 512
#define HDIM 64
#define BN_EPS 1e-5f

// packed CSR entry: {src node, coef = dinv[src]*dinv[dst]} -> one 8B load/store
struct __align__(8) Ent { int u; float c; };

// ---------------- CSR build ----------------

__global__ void count_k(const int* __restrict__ dst, int* __restrict__ deg) {
    int e = blockIdx.x * 256 + threadIdx.x;
    if (e < E_EDGES) atomicAdd(&deg[dst[e]], 1);
}

__global__ void dinv_k(const int* __restrict__ deg, float* __restrict__ dinv) {
    int v = blockIdx.x * 256 + threadIdx.x;
    if (v < N_NODES) dinv[v] = rsqrtf((float)(deg[v] + 1));
}

__global__ void scan1_k(const int* __restrict__ deg, int* __restrict__ ptr,
                        int* __restrict__ bsum) {
    __shared__ int sh[256];
    int t = threadIdx.x;
    int i = blockIdx.x * 256 + t;
    int v = (i < N_NODES) ? deg[i] : 0;
    sh[t] = v;
    __syncthreads();
    for (int off = 1; off < 256; off <<= 1) {
        int add = (t >= off) ? sh[t - off] : 0;
        __syncthreads();
        sh[t] += add;
        __syncthreads();
    }
    if (i < N_NODES) ptr[i] = sh[t] - v;      // exclusive within block
    if (t == 255) bsum[blockIdx.x] = sh[255]; // block total
}

__global__ void scan2_k(int* __restrict__ bsum, int nb) {
    __shared__ int sh[512];
    int t = threadIdx.x;
    int v = (t < nb) ? bsum[t] : 0;
    sh[t] = v;
    __syncthreads();
    for (int off = 1; off < 512; off <<= 1) {
        int add = (t >= off) ? sh[t - off] : 0;
        __syncthreads();
        sh[t] += add;
        __syncthreads();
    }
    if (t < nb) bsum[t] = sh[t] - v; // exclusive block offsets
}

__global__ void scan3_k(int* __restrict__ ptr, const int* __restrict__ bsum) {
    int i = blockIdx.x * 256 + threadIdx.x;
    if (i < N_NODES) ptr[i] += bsum[i >> 8];
    if (i == 0) ptr[N_NODES] = E_EDGES;
}

// fill CSR + fused layer-1 scalar aggregation (x is [N,1] so layer 1 is rank-1:
// s[v] = sum_e coef*x[u]; self-loop term added in l1_expand_k)
__global__ void fill_fused_k(const int* __restrict__ src, const int* __restrict__ dst,
                             const float* __restrict__ x, const int* __restrict__ ptr,
                             int* __restrict__ fillc, Ent* __restrict__ csr,
                             const float* __restrict__ dinv, float* __restrict__ sbuf) {
    int e = blockIdx.x * 256 + threadIdx.x;
    if (e >= E_EDGES) return;
    int v = dst[e];
    int u = src[e];
    float c = dinv[u] * dinv[v];
    int k = atomicAdd(&fillc[v], 1);
    Ent en; en.u = u; en.c = c;
    csr[ptr[v] + k] = en;                 // single 8B scattered store
    atomicAdd(&sbuf[v], c * x[u]);        // fused layer-1 edge aggregation
}

// layer 1 expand: x1[v,f] = relu(bn((s_full[v]*w1[f]+b1[f])))
__global__ void l1_expand_k(const float* __restrict__ sbuf, const float* __restrict__ x,
                            const float* __restrict__ dinv,
                            const float* __restrict__ w1, const float* __restrict__ b1,
                            const float* __restrict__ bg, const float* __restrict__ bb,
                            const float* __restrict__ brm, const float* __restrict__ brv,
                            float* __restrict__ xout) {
    int tid = blockIdx.x * 256 + threadIdx.x;
    if (tid >= N_NODES * HDIM) return;
    int v = tid >> 6;
    int f = tid & 63;
    float dv = dinv[v];
    float s = sbuf[v] + dv * dv * x[v];   // add self-loop
    float sc = bg[f] * rsqrtf(brv[f] + BN_EPS);
    float val = (s * w1[f] + b1[f] - brm[f]) * sc + bb[f];
    xout[tid] = fmaxf(val, 0.f);
}

// ---------------- Layers 2/3: aggregate(x) then @W + b + BN + ReLU ----------------
// One wave per node. Lane layout (q = lane>>4, s = lane&15): quarter q handles
// edges e+q (mod 4); each lane loads a float4 of features (16 lanes x 16B = full
// 256B row, one dwordx4). Unroll x2 -> 2 independent row gathers in flight/wave.

__global__ __launch_bounds__(256) void agg_gemm_k(
    const float* __restrict__ xin, float* __restrict__ xout,
    const int* __restrict__ ptr, const Ent* __restrict__ csr,
    const float* __restrict__ dinv,
    const float* __restrict__ W, const float* __restrict__ bias,
    const float* __restrict__ bg, const float* __restrict__ bb,
    const float* __restrict__ brm, const float* __restrict__ brv) {
    __shared__ float wsh[HDIM * HDIM]; // 16 KB
    __shared__ float sM[HDIM], sC[HDIM];
    int tid = threadIdx.x;
    for (int i = tid; i < HDIM * HDIM; i += 256) wsh[i] = W[i];
    if (tid < HDIM) {
        float sc = bg[tid] * rsqrtf(brv[tid] + BN_EPS);
        sM[tid] = sc;
        sC[tid] = (bias[tid] - brm[tid]) * sc + bb[tid];
    }
    __syncthreads();

    int lane = tid & 63;
    int v = (blockIdx.x << 2) + (tid >> 6);
    if (v >= N_NODES) return;
    int q = lane >> 4;
    int s = lane & 15;

    const float4* __restrict__ xin4 = (const float4*)xin;
    int e0 = ptr[v], e1 = ptr[v + 1];
    float4 acc = {0.f, 0.f, 0.f, 0.f};

    for (int e = e0; e < e1; e += 8) {
#pragma unroll
        for (int j = 0; j < 2; j++) {
            int ee = e + j * 4 + q;
            int eidx = (ee < e1) ? ee : (e1 - 1);
            Ent en = csr[eidx];                   // 8B, broadcast within quarter
            float c = (ee < e1) ? en.c : 0.f;
            float4 row = xin4[(size_t)en.u * 16 + s]; // coalesced 16B/lane
            acc.x += c * row.x; acc.y += c * row.y;
            acc.z += c * row.z; acc.w += c * row.w;
        }
    }
    float dv = dinv[v];
    if (q == 0) { // self-loop added by quarter 0 only
        float4 xv = xin4[(size_t)v * 16 + s];
        float c = dv * dv;
        acc.x += c * xv.x; acc.y += c * xv.y;
        acc.z += c * xv.z; acc.w += c * xv.w;
    }

    // reduce partial sums across the 4 quarters (lanes with equal s)
    float a4[4] = {acc.x, acc.y, acc.z, acc.w};
#pragma unroll
    for (int i = 0; i < 4; i++) {
        a4[i] += __shfl_xor(a4[i], 16);
        a4[i] += __shfl_xor(a4[i], 32);
    }

    // epilogue GEMM: lane = output feature; agg[k] lives on lane k>>2, comp k&3
    int f = lane;
    float o = 0.f;
#pragma unroll
    for (int k = 0; k < HDIM; k++) {
        float a = __shfl(a4[k & 3], k >> 2);
        o += a * wsh[(k << 6) + f]; // 2-way bank alias = free
    }
    xout[(size_t)v * HDIM + f] = fmaxf(o * sM[f] + sC[f], 0.f);
}

// ---------------- Pool (mean/max per graph) + MLP head ----------------

__device__ inline int lower_bound_i(const int* __restrict__ a, int n, int val) {
    int lo = 0, hi = n;
    while (lo < hi) {
        int mid = (lo + hi) >> 1;
        if (a[mid] < val) lo = mid + 1; else hi = mid;
    }
    return lo;
}

__global__ void pool_mlp_k(const float* __restrict__ x, const int* __restrict__ batch,
                           const float* __restrict__ wl1, const float* __restrict__ bl1,
                           const float* __restrict__ wl2, const float* __restrict__ bl2,
                           const float* __restrict__ bg, const float* __restrict__ bb,
                           const float* __restrict__ brm, const float* __restrict__ brv,
                           float* __restrict__ out) {
    int g = blockIdx.x;
    int tid = threadIdx.x;
    int w = tid >> 6;   // wave 0..3
    int f = tid & 63;
    int start = lower_bound_i(batch, N_NODES, g);
    int end = lower_bound_i(batch, N_NODES, g + 1);
    float sum = 0.f;
    float mx = -3.402823466e38f;
#pragma unroll 2
    for (int v = start + w; v < end; v += 4) {
        float val = x[(size_t)v * HDIM + f];
        sum += val;
        mx = fmaxf(mx, val);
    }
    __shared__ float ssum[4][HDIM], smax[4][HDIM];
    __shared__ float zs[2 * HDIM];
    ssum[w][f] = sum;
    smax[w][f] = mx;
    __syncthreads();
    if (tid < 64) {
        float sm = ssum[0][f] + ssum[1][f] + ssum[2][f] + ssum[3][f];
        float m = fmaxf(fmaxf(smax[0][f], smax[1][f]), fmaxf(smax[2][f], smax[3][f]));
        float cnt = (float)(end - start);
        zs[f] = sm / fmaxf(cnt, 1.f);
        zs[HDIM + f] = m;
    }
    __syncthreads();
    if (tid >= 64) return;

    float o = bl1[f];
#pragma unroll 8
    for (int k = 0; k < 2 * HDIM; k++) {
        o += zs[k] * wl1[k * HDIM + f];
    }
    float sc = bg[f] * rsqrtf(brv[f] + BN_EPS);
    o = fmaxf((o - brm[f]) * sc + bb[f], 0.f);

    float p0 = o * wl2[f * 2 + 0];
    float p1 = o * wl2[f * 2 + 1];
    for (int off = 32; off > 0; off >>= 1) {
        p0 += __shfl_down(p0, off);
        p1 += __shfl_down(p1, off);
    }
    if (f == 0) {
        out[g * 2 + 0] = p0 + bl2[0];
        out[g * 2 + 1] = p1 + bl2[1];
    }
}

// ---------------- launch ----------------

extern "C" void kernel_launch(void* const* d_in, const int* in_sizes, int n_in,
                              void* d_out, int out_size, void* d_ws, size_t ws_size,
                              hipStream_t stream) {
    const float* x    = (const float*)d_in[0];
    const int* src    = (const int*)d_in[1];
    const int* dst    = (const int*)d_in[2];
    const int* batch  = (const int*)d_in[3];
    const float* w1   = (const float*)d_in[4];
    const float* b1   = (const float*)d_in[5];
    const float* w2   = (const float*)d_in[6];
    const float* b2   = (const float*)d_in[7];
    const float* w3   = (const float*)d_in[8];
    const float* b3   = (const float*)d_in[9];
    const float* wl1  = (const float*)d_in[10];
    const float* bl1  = (const float*)d_in[11];
    const float* wl2  = (const float*)d_in[12];
    const float* bl2  = (const float*)d_in[13];
    const float* bn1g = (const float*)d_in[14];
    const float* bn1b = (const float*)d_in[15];
    const float* bn1rm = (const float*)d_in[16];
    const float* bn1rv = (const float*)d_in[17];
    const float* bn2g = (const float*)d_in[18];
    const float* bn2b = (const float*)d_in[19];
    const float* bn2rm = (const float*)d_in[20];
    const float* bn2rv = (const float*)d_in[21];
    const float* bn3g = (const float*)d_in[22];
    const float* bn3b = (const float*)d_in[23];
    const float* bn3rm = (const float*)d_in[24];
    const float* bn3rv = (const float*)d_in[25];
    const float* bnlg = (const float*)d_in[26];
    const float* bnlb = (const float*)d_in[27];
    const float* bnlrm = (const float*)d_in[28];
    const float* bnlrv = (const float*)d_in[29];
    float* out = (float*)d_out;

    char* ws = (char*)d_ws;
    size_t off = 0;
    auto alloc = [&](size_t bytes) -> char* {
        off = (off + 255) & ~(size_t)255;
        char* p = ws + off;
        off += bytes;
        return p;
    };
    int*   deg_i = (int*)alloc((size_t)N_NODES * 4);
    float* dinv  = (float*)alloc((size_t)N_NODES * 4);
    int*   ptr   = (int*)alloc(((size_t)N_NODES + 1) * 4);
    int*   fillc = (int*)alloc((size_t)N_NODES * 4);
    int*   bsum  = (int*)alloc(1024 * 4);
    Ent*   csr   = (Ent*)alloc((size_t)E_EDGES * 8);
    float* sbuf  = (float*)alloc((size_t)N_NODES * 4);
    float* xa    = (float*)alloc((size_t)N_NODES * HDIM * 4);
    float* xb    = (float*)alloc((size_t)N_NODES * HDIM * 4);
    if (off > ws_size) {
        fprintf(stderr, "kernel_launch: ws too small (%zu > %zu)\n", off, ws_size);
    }

    const int NB_N  = (N_NODES + 255) / 256;
    const int NB_E  = (E_EDGES + 255) / 256;
    const int NB_NH = (N_NODES * HDIM + 255) / 256;
    const int NB_WV = (N_NODES + 3) / 4;

    hipMemsetAsync(deg_i, 0, (size_t)N_NODES * 4, stream);
    hipMemsetAsync(fillc, 0, (size_t)N_NODES * 4, stream);
    hipMemsetAsync(sbuf, 0, (size_t)N_NODES * 4, stream);

    count_k<<<NB_E, 256, 0, stream>>>(dst, deg_i);
    dinv_k<<<NB_N, 256, 0, stream>>>(deg_i, dinv);
    scan1_k<<<NB_N, 256, 0, stream>>>(deg_i, ptr, bsum);
    scan2_k<<<1, 512, 0, stream>>>(bsum, NB_N);
    scan3_k<<<NB_N, 256, 0, stream>>>(ptr, bsum);
    fill_fused_k<<<NB_E, 256, 0, stream>>>(src, dst, x, ptr, fillc, csr, dinv, sbuf);

    l1_expand_k<<<NB_NH, 256, 0, stream>>>(sbuf, x, dinv, w1, b1,
                                           bn1g, bn1b, bn1rm, bn1rv, xa);

    agg_gemm_k<<<NB_WV, 256, 0, stream>>>(xa, xb, ptr, csr, dinv,
                                          w2, b2, bn2g, bn2b, bn2rm, bn2rv);
    agg_gemm_k<<<NB_WV, 256, 0, stream>>>(xb, xa, ptr, csr, dinv,
                                          w3, b3, bn3g, bn3b, bn3rm, bn3rv);

    pool_mlp_k<<<N_GRAPH, 256, 0, stream>>>(xa, batch, wl1, bl1, wl2, bl2,
                                            bnlg, bnlb, bnlrm, bnlrv, out);
}